// Round 19
// baseline (95.870 us; speedup 1.0000x reference)
//
#include <hip/hip_runtime.h>
#include <math.h>

#define N_NODES 50000
#define E_EDGES 800000
#define F_INDIM 128
#define HID 32
#define C_OUT 16

#define BSH 6          // 64 nodes per bucket
#define BNODE 64
#define NB 782         // ceil(50000/64)
#define BCAP 1280      // arena capacity per bucket (mean 1024, +8 sigma)
#define BINA_BLKS 256
#define CH 3125        // edges per binA block: 256*3125 = 800000 exactly

#define K1ROWS 128     // rows per k1 block (512 threads, 8 rows/thread)
#define K1PAD 136      // sxT row pad (128 rows + 8)
#define KC 32          // K-chunk (4 chunks of 32)
#define K1BLKS 391     // ceil(50000/128)

typedef unsigned long long u64;
typedef unsigned short ushort_t;

__device__ __forceinline__ ushort_t bf16rne(float f) {
    unsigned u = __float_as_uint(f);
    return (ushort_t)((u + 0x7FFFu + ((u >> 16) & 1u)) >> 16);
}
__device__ __forceinline__ float bf16tof(ushort_t b) {
    return __uint_as_float((unsigned)b << 16);
}

// ---- FUSED (512 thr): blocks 0..255 = binA; 256..646 = k1 ---------------
__global__ __launch_bounds__(512) void k_fuseA(
        const float* __restrict__ x,
        const float* __restrict__ Wrel, const float* __restrict__ Wroot,
        const float* __restrict__ b1,
        const int* __restrict__ ei, const float* __restrict__ ea,
        int* __restrict__ bcur, u64* __restrict__ arena,
        ushort_t* __restrict__ t1b, ushort_t* __restrict__ t2c) {
    __shared__ __align__(16) char smem[25600];
    const int tid = threadIdx.x;

    if (blockIdx.x < BINA_BLKS) {
        // ===== binA: hist -> reserve (base-relative) -> direct write =====
        int* hist = (int*)smem;            // NB
        int* cur  = hist + NB;             // NB
        int* gb   = cur + NB;              // NB  (3*782*4 = 9384B)
        const int e0 = blockIdx.x * CH;

        for (int i = tid; i < NB; i += 512) hist[i] = 0;
        __syncthreads();
        for (int k = tid; k < CH; k += 512)
            atomicAdd(&hist[ei[E_EDGES + e0 + k] >> BSH], 1);
        __syncthreads();
        for (int i = tid; i < NB; i += 512) {
            int b = i + blockIdx.x; if (b >= NB) b -= NB;
            int cnt = hist[b];
            gb[b] = b * BCAP + (cnt ? atomicAdd(&bcur[b], cnt) : 0);
            cur[b] = 0;
        }
        __syncthreads();
        for (int k = tid; k < CH; k += 512) {
            int e = e0 + k;
            int src = ei[e];
            int dst = ei[E_EDGES + e];
            float w = ea[e];
            int bkt = dst >> BSH;
            int p = atomicAdd(&cur[bkt], 1);
            unsigned lo = (unsigned)src | ((unsigned)(dst & (BNODE - 1)) << 16);
            arena[(size_t)gb[bkt] + p] = (u64)lo | ((u64)__float_as_uint(w) << 32);
        }
    } else {
        // ===== k1_dense: 128 rows/block, K chunked 4 x 32 =====
        float (*sW)[64] = (float(*)[64])smem;                    // [KC][64] 8KB
        float (*sxT)[K1PAD] = (float(*)[K1PAD])(smem + 8192);    // [KC][136] 17.4KB
        const int rowBase = (blockIdx.x - BINA_BLKS) * K1ROWS;
        const int c = tid & 31;
        const int g = tid >> 5;          // 0..15: 8-row groups
        const float4* x4 = (const float4*)x;

        float acc1[8], acc2[8];
#pragma unroll
        for (int i = 0; i < 8; ++i) { acc1[i] = 0.f; acc2[i] = 0.f; }

        for (int kc = 0; kc < F_INDIM / KC; ++kc) {
            const int k0 = kc * KC;
            for (int i = tid; i < KC * 64; i += 512) {
                int k = i >> 6, j = i & 63;
                int cc = j >> 1, m = j & 1;
                sW[k][j] = m ? Wroot[(k0 + k) * HID + cc]
                             : Wrel[(k0 + k) * HID + cc];
            }
            for (int i = tid; i < K1ROWS * (KC / 4); i += 512) {
                int r = i >> 3, q = i & 7;
                int row = rowBase + r;
                float4 v = make_float4(0.f, 0.f, 0.f, 0.f);
                if (row < N_NODES) v = x4[(size_t)row * 32 + (k0 >> 2) + q];
                sxT[4 * q + 0][r] = v.x;
                sxT[4 * q + 1][r] = v.y;
                sxT[4 * q + 2][r] = v.z;
                sxT[4 * q + 3][r] = v.w;
            }
            __syncthreads();
#pragma unroll 4
            for (int k = 0; k < KC; ++k) {
                float2 w = *(const float2*)&sW[k][2 * c];
                float4 xa = *(const float4*)&sxT[k][8 * g];
                float4 xb = *(const float4*)&sxT[k][8 * g + 4];
                acc1[0] = fmaf(xa.x, w.x, acc1[0]); acc2[0] = fmaf(xa.x, w.y, acc2[0]);
                acc1[1] = fmaf(xa.y, w.x, acc1[1]); acc2[1] = fmaf(xa.y, w.y, acc2[1]);
                acc1[2] = fmaf(xa.z, w.x, acc1[2]); acc2[2] = fmaf(xa.z, w.y, acc2[2]);
                acc1[3] = fmaf(xa.w, w.x, acc1[3]); acc2[3] = fmaf(xa.w, w.y, acc2[3]);
                acc1[4] = fmaf(xb.x, w.x, acc1[4]); acc2[4] = fmaf(xb.x, w.y, acc2[4]);
                acc1[5] = fmaf(xb.y, w.x, acc1[5]); acc2[5] = fmaf(xb.y, w.y, acc2[5]);
                acc1[6] = fmaf(xb.z, w.x, acc1[6]); acc2[6] = fmaf(xb.z, w.y, acc2[6]);
                acc1[7] = fmaf(xb.w, w.x, acc1[7]); acc2[7] = fmaf(xb.w, w.y, acc2[7]);
            }
            __syncthreads();
        }

        const float bc = b1[c];
#pragma unroll
        for (int i = 0; i < 8; ++i) {
            int row = rowBase + 8 * g + i;
            if (row < N_NODES) {
                t1b[(size_t)row * HID + c] = bf16rne(acc1[i]);
                t2c[(size_t)row * HID + c] = bf16rne(acc2[i] + bc);
            }
        }
    }
}

// ---- phase B: per-bucket (64 nodes) local sort; 782 blocks --------------
__global__ __launch_bounds__(256) void k_binB(const int* __restrict__ bcur,
                                              const u64* __restrict__ arena,
                                              unsigned* __restrict__ erec,
                                              int* __restrict__ rowptr) {
    __shared__ int cur[BNODE];
    __shared__ int hist[BNODE];
    __shared__ int sbase;
    const int tid = threadIdx.x;
    const int b = blockIdx.x;
    if (tid < 64) {
        int acc = 0;
        for (int i = tid; i < b; i += 64) acc += bcur[i];
#pragma unroll
        for (int d = 1; d < 64; d <<= 1) acc += __shfl_xor(acc, d);
        if (tid == 0) sbase = acc;
    }
    if (tid < BNODE) hist[tid] = 0;
    __syncthreads();
    const int cnt = bcur[b];
    const u64* seg = arena + (size_t)b * BCAP;
    for (int i = tid; i < cnt; i += 256)
        atomicAdd(&hist[((unsigned)seg[i] >> 16) & (BNODE - 1)], 1);
    __syncthreads();
    if (tid < 64) {   // single-wave 64-scan
        int v = hist[tid];
        int inc = v;
#pragma unroll
        for (int d = 1; d < 64; d <<= 1) {
            int t = __shfl_up(inc, d);
            if (tid >= d) inc += t;
        }
        int ex = inc - v;
        cur[tid] = ex;
        int node = (b << BSH) + tid;
        if (node < N_NODES) rowptr[node] = sbase + ex;
    }
    if (b == NB - 1 && tid == 0) rowptr[N_NODES] = E_EDGES;
    __syncthreads();
    const int gbase = sbase;
    for (int i = tid; i < cnt; i += 256) {
        u64 r = seg[i];
        unsigned lo = (unsigned)r;
        int dl = (lo >> 16) & (BNODE - 1);
        int p = atomicAdd(&cur[dl], 1);
        unsigned wu = (unsigned)(r >> 32);
        unsigned wb = (wu + 0x7FFFu + ((wu >> 16) & 1u)) & 0xFFFF0000u;
        erec[gbase + p] = wb | (lo & 0xFFFFu);
    }
}

// ---- Gather layer 1 FUSED with layer-2 dense ----------------------------
// wave per node; 8 lanes/edge x 4 accumulator slots = 32 edges in flight.
__global__ __launch_bounds__(256) void k_gather1(
        const int* __restrict__ rowptr, const unsigned* __restrict__ erec,
        const ushort_t* __restrict__ t1b, const ushort_t* __restrict__ t2c,
        const float* __restrict__ Wrel2, const float* __restrict__ Wroot2,
        const float* __restrict__ b2,
        ushort_t* __restrict__ u1b, float* __restrict__ u2b) {
    __shared__ float hbuf[4][HID];   // 512B
    const int tid = threadIdx.x;
    const int lane = tid & 63;
    const int wid = tid >> 6;

    const int node = blockIdx.x * 4 + wid;   // grid exact, always < N_NODES
    const int start = rowptr[node];
    const int end = rowptr[node + 1];

    const int er2 = lane >> 5;
    const int j = lane & 31;
    const float* Wsel = (j < 16) ? (Wrel2 + (j & 15)) : (Wroot2 + (j & 15));
    float w2r[16];
#pragma unroll
    for (int kk = 0; kk < 16; ++kk)
        w2r[kk] = Wsel[(er2 * 16 + kk) * C_OUT];

    const int er = lane >> 3;        // 0..7: edge slot
    const int c4 = lane & 7;         // cols 4c4..4c4+3
    float A[4][4];
#pragma unroll
    for (int s = 0; s < 4; ++s)
#pragma unroll
        for (int q = 0; q < 4; ++q) A[s][q] = 0.f;

    int e = start + er;
    for (; e + 24 < end; e += 32) {
#pragma unroll
        for (int s = 0; s < 4; ++s) {
            unsigned r = erec[e + 8 * s];
            float w = __uint_as_float(r & 0xFFFF0000u);
            ushort4 p = *(const ushort4*)&t1b[(size_t)(r & 0xFFFFu) * HID + 4 * c4];
            A[s][0] = fmaf(w, bf16tof(p.x), A[s][0]);
            A[s][1] = fmaf(w, bf16tof(p.y), A[s][1]);
            A[s][2] = fmaf(w, bf16tof(p.z), A[s][2]);
            A[s][3] = fmaf(w, bf16tof(p.w), A[s][3]);
        }
    }
    for (; e < end; e += 8) {
        unsigned r = erec[e];
        float w = __uint_as_float(r & 0xFFFF0000u);
        ushort4 p = *(const ushort4*)&t1b[(size_t)(r & 0xFFFFu) * HID + 4 * c4];
        A[0][0] = fmaf(w, bf16tof(p.x), A[0][0]);
        A[0][1] = fmaf(w, bf16tof(p.y), A[0][1]);
        A[0][2] = fmaf(w, bf16tof(p.z), A[0][2]);
        A[0][3] = fmaf(w, bf16tof(p.w), A[0][3]);
    }
    float ax = A[0][0] + A[1][0] + A[2][0] + A[3][0];
    float ay = A[0][1] + A[1][1] + A[2][1] + A[3][1];
    float az = A[0][2] + A[1][2] + A[2][2] + A[3][2];
    float aw = A[0][3] + A[1][3] + A[2][3] + A[3][3];
#pragma unroll
    for (int d = 8; d < 64; d <<= 1) {
        ax += __shfl_xor(ax, d);
        ay += __shfl_xor(ay, d);
        az += __shfl_xor(az, d);
        aw += __shfl_xor(aw, d);
    }
    ushort4 t2u = *(const ushort4*)&t2c[(size_t)node * HID + 4 * c4];
    float4 hv;
    hv.x = ax + bf16tof(t2u.x); hv.x = hv.x > 0.f ? hv.x : 0.f;
    hv.y = ay + bf16tof(t2u.y); hv.y = hv.y > 0.f ? hv.y : 0.f;
    hv.z = az + bf16tof(t2u.z); hv.z = hv.z > 0.f ? hv.z : 0.f;
    hv.w = aw + bf16tof(t2u.w); hv.w = hv.w > 0.f ? hv.w : 0.f;
    if (er == 0) *(float4*)&hbuf[wid][4 * c4] = hv;
    __syncthreads();

    float outv = 0.f;
#pragma unroll
    for (int kk = 0; kk < 16; ++kk)
        outv = fmaf(hbuf[wid][er2 * 16 + kk], w2r[kk], outv);
    outv += __shfl_xor(outv, 32);
    if (er2 == 0) {
        int cc = j & 15;
        if (j < 16) u1b[(size_t)node * C_OUT + cc] = bf16rne(outv);
        else        u2b[(size_t)node * C_OUT + cc] = outv + b2[cc];
    }
}

// ---- Gather layer 2 (fused +u2b, log_softmax) ---------------------------
// 8 lanes/edge x 4 accumulator slots = 32 edges in flight.
__global__ __launch_bounds__(256) void k_gather2(
        const int* __restrict__ rowptr, const unsigned* __restrict__ erec,
        const ushort_t* __restrict__ u1b, const float* __restrict__ u2b,
        float* __restrict__ out) {
    const int tid = threadIdx.x;
    const int lane = tid & 63;
    const int node = blockIdx.x * 4 + (tid >> 6);
    const int start = rowptr[node];
    const int end = rowptr[node + 1];
    const int er = lane >> 3;        // 0..7: edge slot
    const int c2 = lane & 7;         // column pair
    float AX[4], AY[4];
#pragma unroll
    for (int s = 0; s < 4; ++s) { AX[s] = 0.f; AY[s] = 0.f; }

    int e = start + er;
    for (; e + 24 < end; e += 32) {
#pragma unroll
        for (int s = 0; s < 4; ++s) {
            unsigned r = erec[e + 8 * s];
            float w = __uint_as_float(r & 0xFFFF0000u);
            ushort2 p = *(const ushort2*)&u1b[(size_t)(r & 0xFFFFu) * C_OUT + 2 * c2];
            AX[s] = fmaf(w, bf16tof(p.x), AX[s]);
            AY[s] = fmaf(w, bf16tof(p.y), AY[s]);
        }
    }
    for (; e < end; e += 8) {
        unsigned r = erec[e];
        float w = __uint_as_float(r & 0xFFFF0000u);
        ushort2 p = *(const ushort2*)&u1b[(size_t)(r & 0xFFFFu) * C_OUT + 2 * c2];
        AX[0] = fmaf(w, bf16tof(p.x), AX[0]);
        AY[0] = fmaf(w, bf16tof(p.y), AY[0]);
    }
    float ax = AX[0] + AX[1] + AX[2] + AX[3];
    float ay = AY[0] + AY[1] + AY[2] + AY[3];
    ax += __shfl_xor(ax, 8);  ay += __shfl_xor(ay, 8);
    ax += __shfl_xor(ax, 16); ay += __shfl_xor(ay, 16);
    ax += __shfl_xor(ax, 32); ay += __shfl_xor(ay, 32);
    float2 u2 = *(const float2*)&u2b[(size_t)node * C_OUT + 2 * c2];
    float vx = ax + u2.x;
    float vy = ay + u2.y;
    float mx = fmaxf(vx, vy);
#pragma unroll
    for (int d = 1; d < 8; d <<= 1) mx = fmaxf(mx, __shfl_xor(mx, d));
    float s = expf(vx - mx) + expf(vy - mx);
#pragma unroll
    for (int d = 1; d < 8; d <<= 1) s += __shfl_xor(s, d);
    float lse = mx + logf(s);
    if (er == 0)
        *(float2*)&out[(size_t)node * C_OUT + 2 * c2] = make_float2(vx - lse, vy - lse);
}

extern "C" void kernel_launch(void* const* d_in, const int* in_sizes, int n_in,
                              void* d_out, int out_size, void* d_ws, size_t ws_size,
                              hipStream_t stream) {
    const float* x      = (const float*)d_in[0];
    const int*   ei     = (const int*)d_in[1];
    const float* ea     = (const float*)d_in[2];
    const float* Wrel1  = (const float*)d_in[3];
    const float* Wroot1 = (const float*)d_in[4];
    const float* b1     = (const float*)d_in[5];
    const float* Wrel2  = (const float*)d_in[6];
    const float* Wroot2 = (const float*)d_in[7];
    const float* b2     = (const float*)d_in[8];
    float* out = (float*)d_out;

    float* ws = (float*)d_ws;
    float*    u2b  = ws;                                   // N*16 f32
    ushort_t* t1b  = (ushort_t*)(ws + 800000);             // N*32 bf16
    ushort_t* t2c  = (ushort_t*)(ws + 1600000);            // N*32 bf16
    ushort_t* u1b  = (ushort_t*)(ws + 2400000);            // N*16 bf16
    u64*      arena = (u64*)(ws + 2600000);                // NB*BCAP u64
    unsigned* erec = (unsigned*)(ws + 2600000 + (size_t)NB * BCAP * 2); // E u32
    int*      bcur   = (int*)(erec + E_EDGES);             // NB
    int*      rowptr = bcur + NB;                          // N+1

    (void)hipMemsetAsync(bcur, 0, NB * sizeof(int), stream);
    k_fuseA<<<BINA_BLKS + K1BLKS, 512, 0, stream>>>(
        x, Wrel1, Wroot1, b1, ei, ea, bcur, arena, t1b, t2c);
    k_binB<<<NB, 256, 0, stream>>>(bcur, arena, erec, rowptr);
    k_gather1<<<N_NODES / 4, 256, 0, stream>>>(
        rowptr, erec, t1b, t2c, Wrel2, Wroot2, b2, u1b, u2b);
    k_gather2<<<N_NODES / 4, 256, 0, stream>>>(rowptr, erec, u1b, u2b, out);
}

// Round 20
// 88.432 us; speedup vs baseline: 1.0841x; 1.0841x over previous
//
#include <hip/hip_runtime.h>
#include <math.h>

#define N_NODES 50000
#define E_EDGES 800000
#define F_INDIM 128
#define HID 32
#define C_OUT 16

#define BSH 6          // 64 nodes per bucket
#define BNODE 64
#define NB 782         // ceil(50000/64)
#define BCAP 1280      // arena capacity per bucket (mean 1024, +8 sigma)
#define BINA_BLKS 128
#define CH 6250        // edges per binA block: 128*6250 = 800000 exactly

#define K1ROWS 128     // rows per k1 block (512 threads, 8 rows/thread)
#define K1PAD 136      // sxT row pad (128 rows + 8)
#define KC 32          // K-chunk (4 chunks of 32)
#define K1BLKS 391     // ceil(50000/128)

typedef unsigned long long u64;
typedef unsigned short ushort_t;

__device__ __forceinline__ ushort_t bf16rne(float f) {
    unsigned u = __float_as_uint(f);
    return (ushort_t)((u + 0x7FFFu + ((u >> 16) & 1u)) >> 16);
}
__device__ __forceinline__ float bf16tof(ushort_t b) {
    return __uint_as_float((unsigned)b << 16);
}

// ---- FUSED (512 thr): blocks 0..127 = binA; 128..518 = k1 ---------------
__global__ __launch_bounds__(512) void k_fuseA(
        const float* __restrict__ x,
        const float* __restrict__ Wrel, const float* __restrict__ Wroot,
        const float* __restrict__ b1,
        const int* __restrict__ ei, const float* __restrict__ ea,
        int* __restrict__ bcur, u64* __restrict__ arena,
        ushort_t* __restrict__ t1b, ushort_t* __restrict__ t2c) {
    __shared__ __align__(16) char smem[25600];
    const int tid = threadIdx.x;

    if (blockIdx.x < BINA_BLKS) {
        // ===== binA: hist -> reserve -> direct write =====
        // 128 blocks: mean (block,bucket) run = 8 recs = 64B = full line.
        int* hist = (int*)smem;            // NB
        int* cur  = hist + NB;             // NB
        int* gb   = cur + NB;              // NB  (3*782*4 = 9384B)
        const int e0 = blockIdx.x * CH;

        for (int i = tid; i < NB; i += 512) hist[i] = 0;
        __syncthreads();
        for (int k = tid; k < CH; k += 512)
            atomicAdd(&hist[ei[E_EDGES + e0 + k] >> BSH], 1);
        __syncthreads();
        for (int i = tid; i < NB; i += 512) {
            int b = i + blockIdx.x; if (b >= NB) b -= NB;
            int cnt = hist[b];
            gb[b] = b * BCAP + (cnt ? atomicAdd(&bcur[b], cnt) : 0);
            cur[b] = 0;
        }
        __syncthreads();
        for (int k = tid; k < CH; k += 512) {
            int e = e0 + k;
            int src = ei[e];
            int dst = ei[E_EDGES + e];
            float w = ea[e];
            int bkt = dst >> BSH;
            int p = atomicAdd(&cur[bkt], 1);
            unsigned lo = (unsigned)src | ((unsigned)(dst & (BNODE - 1)) << 16);
            arena[(size_t)gb[bkt] + p] = (u64)lo | ((u64)__float_as_uint(w) << 32);
        }
    } else {
        // ===== k1_dense: 128 rows/block, K chunked 4 x 32 =====
        float (*sW)[64] = (float(*)[64])smem;                    // [KC][64] 8KB
        float (*sxT)[K1PAD] = (float(*)[K1PAD])(smem + 8192);    // [KC][136] 17.4KB
        const int rowBase = (blockIdx.x - BINA_BLKS) * K1ROWS;
        const int c = tid & 31;
        const int g = tid >> 5;          // 0..15: 8-row groups
        const float4* x4 = (const float4*)x;

        float acc1[8], acc2[8];
#pragma unroll
        for (int i = 0; i < 8; ++i) { acc1[i] = 0.f; acc2[i] = 0.f; }

        for (int kc = 0; kc < F_INDIM / KC; ++kc) {
            const int k0 = kc * KC;
            for (int i = tid; i < KC * 64; i += 512) {
                int k = i >> 6, j = i & 63;
                int cc = j >> 1, m = j & 1;
                sW[k][j] = m ? Wroot[(k0 + k) * HID + cc]
                             : Wrel[(k0 + k) * HID + cc];
            }
            for (int i = tid; i < K1ROWS * (KC / 4); i += 512) {
                int r = i >> 3, q = i & 7;
                int row = rowBase + r;
                float4 v = make_float4(0.f, 0.f, 0.f, 0.f);
                if (row < N_NODES) v = x4[(size_t)row * 32 + (k0 >> 2) + q];
                sxT[4 * q + 0][r] = v.x;
                sxT[4 * q + 1][r] = v.y;
                sxT[4 * q + 2][r] = v.z;
                sxT[4 * q + 3][r] = v.w;
            }
            __syncthreads();
#pragma unroll 4
            for (int k = 0; k < KC; ++k) {
                float2 w = *(const float2*)&sW[k][2 * c];
                float4 xa = *(const float4*)&sxT[k][8 * g];
                float4 xb = *(const float4*)&sxT[k][8 * g + 4];
                acc1[0] = fmaf(xa.x, w.x, acc1[0]); acc2[0] = fmaf(xa.x, w.y, acc2[0]);
                acc1[1] = fmaf(xa.y, w.x, acc1[1]); acc2[1] = fmaf(xa.y, w.y, acc2[1]);
                acc1[2] = fmaf(xa.z, w.x, acc1[2]); acc2[2] = fmaf(xa.z, w.y, acc2[2]);
                acc1[3] = fmaf(xa.w, w.x, acc1[3]); acc2[3] = fmaf(xa.w, w.y, acc2[3]);
                acc1[4] = fmaf(xb.x, w.x, acc1[4]); acc2[4] = fmaf(xb.x, w.y, acc2[4]);
                acc1[5] = fmaf(xb.y, w.x, acc1[5]); acc2[5] = fmaf(xb.y, w.y, acc2[5]);
                acc1[6] = fmaf(xb.z, w.x, acc1[6]); acc2[6] = fmaf(xb.z, w.y, acc2[6]);
                acc1[7] = fmaf(xb.w, w.x, acc1[7]); acc2[7] = fmaf(xb.w, w.y, acc2[7]);
            }
            __syncthreads();
        }

        const float bc = b1[c];
#pragma unroll
        for (int i = 0; i < 8; ++i) {
            int row = rowBase + 8 * g + i;
            if (row < N_NODES) {
                t1b[(size_t)row * HID + c] = bf16rne(acc1[i]);
                t2c[(size_t)row * HID + c] = bf16rne(acc2[i] + bc);
            }
        }
    }
}

// ---- phase B: per-bucket (64 nodes) local sort; 782 blocks --------------
__global__ __launch_bounds__(256) void k_binB(const int* __restrict__ bcur,
                                              const u64* __restrict__ arena,
                                              unsigned* __restrict__ erec,
                                              int* __restrict__ rowptr) {
    __shared__ int cur[BNODE];
    __shared__ int hist[BNODE];
    __shared__ int sbase;
    const int tid = threadIdx.x;
    const int b = blockIdx.x;
    if (tid < 64) {
        int acc = 0;
        for (int i = tid; i < b; i += 64) acc += bcur[i];
#pragma unroll
        for (int d = 1; d < 64; d <<= 1) acc += __shfl_xor(acc, d);
        if (tid == 0) sbase = acc;
    }
    if (tid < BNODE) hist[tid] = 0;
    __syncthreads();
    const int cnt = bcur[b];
    const u64* seg = arena + (size_t)b * BCAP;
    for (int i = tid; i < cnt; i += 256)
        atomicAdd(&hist[((unsigned)seg[i] >> 16) & (BNODE - 1)], 1);
    __syncthreads();
    if (tid < 64) {   // single-wave 64-scan
        int v = hist[tid];
        int inc = v;
#pragma unroll
        for (int d = 1; d < 64; d <<= 1) {
            int t = __shfl_up(inc, d);
            if (tid >= d) inc += t;
        }
        int ex = inc - v;
        cur[tid] = ex;
        int node = (b << BSH) + tid;
        if (node < N_NODES) rowptr[node] = sbase + ex;
    }
    if (b == NB - 1 && tid == 0) rowptr[N_NODES] = E_EDGES;
    __syncthreads();
    const int gbase = sbase;
    for (int i = tid; i < cnt; i += 256) {
        u64 r = seg[i];
        unsigned lo = (unsigned)r;
        int dl = (lo >> 16) & (BNODE - 1);
        int p = atomicAdd(&cur[dl], 1);
        unsigned wu = (unsigned)(r >> 32);
        unsigned wb = (wu + 0x7FFFu + ((wu >> 16) & 1u)) & 0xFFFF0000u;
        erec[gbase + p] = wb | (lo & 0xFFFFu);
    }
}

// ---- Gather layer 1 FUSED with layer-2 dense (R18 proven form) ----------
// wave per node; 8 lanes/edge via ushort4, 2 slots = 16 edges in flight.
__global__ __launch_bounds__(256) void k_gather1(
        const int* __restrict__ rowptr, const unsigned* __restrict__ erec,
        const ushort_t* __restrict__ t1b, const ushort_t* __restrict__ t2c,
        const float* __restrict__ Wrel2, const float* __restrict__ Wroot2,
        const float* __restrict__ b2,
        ushort_t* __restrict__ u1b, float* __restrict__ u2b) {
    __shared__ float hbuf[4][HID];   // 512B
    const int tid = threadIdx.x;
    const int lane = tid & 63;
    const int wid = tid >> 6;

    const int node = blockIdx.x * 4 + wid;   // grid exact, always < N_NODES
    const int start = rowptr[node];
    const int end = rowptr[node + 1];

    const int er2 = lane >> 5;
    const int j = lane & 31;
    const float* Wsel = (j < 16) ? (Wrel2 + (j & 15)) : (Wroot2 + (j & 15));
    float w2r[16];
#pragma unroll
    for (int kk = 0; kk < 16; ++kk)
        w2r[kk] = Wsel[(er2 * 16 + kk) * C_OUT];

    const int er = lane >> 3;        // 0..7: edge slot
    const int c4 = lane & 7;         // cols 4c4..4c4+3
    float ax = 0.f, ay = 0.f, az = 0.f, aw = 0.f;
    float bx = 0.f, by = 0.f, bz = 0.f, bw = 0.f;
    int e = start + er;
    for (; e + 8 < end; e += 16) {
        unsigned r0 = erec[e];
        unsigned r1 = erec[e + 8];
        float w0 = __uint_as_float(r0 & 0xFFFF0000u);
        float w1 = __uint_as_float(r1 & 0xFFFF0000u);
        ushort4 p0 = *(const ushort4*)&t1b[(size_t)(r0 & 0xFFFFu) * HID + 4 * c4];
        ushort4 p1 = *(const ushort4*)&t1b[(size_t)(r1 & 0xFFFFu) * HID + 4 * c4];
        ax = fmaf(w0, bf16tof(p0.x), ax); ay = fmaf(w0, bf16tof(p0.y), ay);
        az = fmaf(w0, bf16tof(p0.z), az); aw = fmaf(w0, bf16tof(p0.w), aw);
        bx = fmaf(w1, bf16tof(p1.x), bx); by = fmaf(w1, bf16tof(p1.y), by);
        bz = fmaf(w1, bf16tof(p1.z), bz); bw = fmaf(w1, bf16tof(p1.w), bw);
    }
    if (e < end) {
        unsigned r0 = erec[e];
        float w0 = __uint_as_float(r0 & 0xFFFF0000u);
        ushort4 p0 = *(const ushort4*)&t1b[(size_t)(r0 & 0xFFFFu) * HID + 4 * c4];
        ax = fmaf(w0, bf16tof(p0.x), ax); ay = fmaf(w0, bf16tof(p0.y), ay);
        az = fmaf(w0, bf16tof(p0.z), az); aw = fmaf(w0, bf16tof(p0.w), aw);
    }
    ax += bx; ay += by; az += bz; aw += bw;
#pragma unroll
    for (int d = 8; d < 64; d <<= 1) {
        ax += __shfl_xor(ax, d);
        ay += __shfl_xor(ay, d);
        az += __shfl_xor(az, d);
        aw += __shfl_xor(aw, d);
    }
    ushort4 t2u = *(const ushort4*)&t2c[(size_t)node * HID + 4 * c4];
    float4 hv;
    hv.x = ax + bf16tof(t2u.x); hv.x = hv.x > 0.f ? hv.x : 0.f;
    hv.y = ay + bf16tof(t2u.y); hv.y = hv.y > 0.f ? hv.y : 0.f;
    hv.z = az + bf16tof(t2u.z); hv.z = hv.z > 0.f ? hv.z : 0.f;
    hv.w = aw + bf16tof(t2u.w); hv.w = hv.w > 0.f ? hv.w : 0.f;
    if (er == 0) *(float4*)&hbuf[wid][4 * c4] = hv;
    __syncthreads();

    float outv = 0.f;
#pragma unroll
    for (int kk = 0; kk < 16; ++kk)
        outv = fmaf(hbuf[wid][er2 * 16 + kk], w2r[kk], outv);
    outv += __shfl_xor(outv, 32);
    if (er2 == 0) {
        int cc = j & 15;
        if (j < 16) u1b[(size_t)node * C_OUT + cc] = bf16rne(outv);
        else        u2b[(size_t)node * C_OUT + cc] = outv + b2[cc];
    }
}

// ---- Gather layer 2 (fused +u2b, log_softmax; R18 proven form) ----------
__global__ __launch_bounds__(256) void k_gather2(
        const int* __restrict__ rowptr, const unsigned* __restrict__ erec,
        const ushort_t* __restrict__ u1b, const float* __restrict__ u2b,
        float* __restrict__ out) {
    const int tid = threadIdx.x;
    const int lane = tid & 63;
    const int node = blockIdx.x * 4 + (tid >> 6);
    const int start = rowptr[node];
    const int end = rowptr[node + 1];
    const int er = lane >> 3;        // 0..7: edge slot
    const int c2 = lane & 7;         // column pair
    float a0x = 0.f, a0y = 0.f, a1x = 0.f, a1y = 0.f;
    int e = start + er;
    for (; e + 8 < end; e += 16) {
        unsigned r0 = erec[e];
        unsigned r1 = erec[e + 8];
        float w0 = __uint_as_float(r0 & 0xFFFF0000u);
        float w1 = __uint_as_float(r1 & 0xFFFF0000u);
        ushort2 p0 = *(const ushort2*)&u1b[(size_t)(r0 & 0xFFFFu) * C_OUT + 2 * c2];
        ushort2 p1 = *(const ushort2*)&u1b[(size_t)(r1 & 0xFFFFu) * C_OUT + 2 * c2];
        a0x = fmaf(w0, bf16tof(p0.x), a0x);
        a0y = fmaf(w0, bf16tof(p0.y), a0y);
        a1x = fmaf(w1, bf16tof(p1.x), a1x);
        a1y = fmaf(w1, bf16tof(p1.y), a1y);
    }
    if (e < end) {
        unsigned r0 = erec[e];
        float w0 = __uint_as_float(r0 & 0xFFFF0000u);
        ushort2 p0 = *(const ushort2*)&u1b[(size_t)(r0 & 0xFFFFu) * C_OUT + 2 * c2];
        a0x = fmaf(w0, bf16tof(p0.x), a0x);
        a0y = fmaf(w0, bf16tof(p0.y), a0y);
    }
    float ax = a0x + a1x;
    float ay = a0y + a1y;
    ax += __shfl_xor(ax, 8);  ay += __shfl_xor(ay, 8);
    ax += __shfl_xor(ax, 16); ay += __shfl_xor(ay, 16);
    ax += __shfl_xor(ax, 32); ay += __shfl_xor(ay, 32);
    float2 u2 = *(const float2*)&u2b[(size_t)node * C_OUT + 2 * c2];
    float vx = ax + u2.x;
    float vy = ay + u2.y;
    float mx = fmaxf(vx, vy);
#pragma unroll
    for (int d = 1; d < 8; d <<= 1) mx = fmaxf(mx, __shfl_xor(mx, d));
    float s = expf(vx - mx) + expf(vy - mx);
#pragma unroll
    for (int d = 1; d < 8; d <<= 1) s += __shfl_xor(s, d);
    float lse = mx + logf(s);
    if (er == 0)
        *(float2*)&out[(size_t)node * C_OUT + 2 * c2] = make_float2(vx - lse, vy - lse);
}

extern "C" void kernel_launch(void* const* d_in, const int* in_sizes, int n_in,
                              void* d_out, int out_size, void* d_ws, size_t ws_size,
                              hipStream_t stream) {
    const float* x      = (const float*)d_in[0];
    const int*   ei     = (const int*)d_in[1];
    const float* ea     = (const float*)d_in[2];
    const float* Wrel1  = (const float*)d_in[3];
    const float* Wroot1 = (const float*)d_in[4];
    const float* b1     = (const float*)d_in[5];
    const float* Wrel2  = (const float*)d_in[6];
    const float* Wroot2 = (const float*)d_in[7];
    const float* b2     = (const float*)d_in[8];
    float* out = (float*)d_out;

    float* ws = (float*)d_ws;
    float*    u2b  = ws;                                   // N*16 f32
    ushort_t* t1b  = (ushort_t*)(ws + 800000);             // N*32 bf16
    ushort_t* t2c  = (ushort_t*)(ws + 1600000);            // N*32 bf16
    ushort_t* u1b  = (ushort_t*)(ws + 2400000);            // N*16 bf16
    u64*      arena = (u64*)(ws + 2600000);                // NB*BCAP u64
    unsigned* erec = (unsigned*)(ws + 2600000 + (size_t)NB * BCAP * 2); // E u32
    int*      bcur   = (int*)(erec + E_EDGES);             // NB
    int*      rowptr = bcur + NB;                          // N+1

    (void)hipMemsetAsync(bcur, 0, NB * sizeof(int), stream);
    k_fuseA<<<BINA_BLKS + K1BLKS, 512, 0, stream>>>(
        x, Wrel1, Wroot1, b1, ei, ea, bcur, arena, t1b, t2c);
    k_binB<<<NB, 256, 0, stream>>>(bcur, arena, erec, rowptr);
    k_gather1<<<N_NODES / 4, 256, 0, stream>>>(
        rowptr, erec, t1b, t2c, Wrel2, Wroot2, b2, u1b, u2b);
    k_gather2<<<N_NODES / 4, 256, 0, stream>>>(rowptr, erec, u1b, u2b, out);
}